// Round 1
// baseline (988.593 us; speedup 1.0000x reference)
//
#include <hip/hip_runtime.h>
#include <hip/hip_bf16.h>

#define NN   100000
#define EE   1600000
#define DIN  128
#define HH   64
#define DEA  8
#define NCLS 2

// ---------- helpers ----------
__device__ __forceinline__ unsigned enc_f32(float f) {
    unsigned u = __float_as_uint(f);
    return (u & 0x80000000u) ? ~u : (u | 0x80000000u);
}
__device__ __forceinline__ float dec_f32(unsigned u) {
    return (u & 0x80000000u) ? __uint_as_float(u & 0x7FFFFFFFu)
                             : __uint_as_float(~u);
}

// ---------- K1: init agg / m / denom ----------
__global__ void k_init(float* agg, unsigned* m_enc, float* denom) {
    int i = blockIdx.x * blockDim.x + threadIdx.x;
    int stride = gridDim.x * blockDim.x;
    for (int idx = i; idx < NN * HH; idx += stride) agg[idx] = 0.f;
    for (int idx = i; idx < NN; idx += stride) {
        m_enc[idx] = 0x007FFFFFu;   // enc(-inf)
        denom[idx] = 0.f;
    }
}

// ---------- K2: h = relu(x@W_enc+b); hg = h@W_gat; s_src/s_dst = hg . a ----------
__global__ __launch_bounds__(256) void k_encode(
        const float* __restrict__ x,
        const float* __restrict__ W_enc, const float* __restrict__ b_enc,
        const float* __restrict__ W_gat,
        const float* __restrict__ a_src, const float* __restrict__ a_dst,
        float* __restrict__ hg, float* __restrict__ s_src, float* __restrict__ s_dst) {
    __shared__ float wenc[DIN * HH];   // 32 KB
    __shared__ float wgat[HH * HH];    // 16 KB
    __shared__ float benc[HH], avs[HH], avd[HH];
    __shared__ float xrow[4][DIN];
    __shared__ float hrow[4][HH];
    int tid = threadIdx.x;
    for (int i = tid; i < DIN * HH; i += 256) wenc[i] = W_enc[i];
    for (int i = tid; i < HH * HH; i += 256) wgat[i] = W_gat[i];
    if (tid < HH) { benc[tid] = b_enc[tid]; avs[tid] = a_src[tid]; avd[tid] = a_dst[tid]; }
    __syncthreads();
    int wave = tid >> 6, lane = tid & 63;
    for (int base = blockIdx.x * 4; base < NN; base += gridDim.x * 4) {
        int node = base + wave;
        bool valid = node < NN;
        if (valid) {
            xrow[wave][lane]      = x[node * DIN + lane];
            xrow[wave][lane + 64] = x[node * DIN + 64 + lane];
        }
        __syncthreads();
        if (valid) {
            float hacc = benc[lane];
            #pragma unroll 8
            for (int d = 0; d < DIN; d++) hacc = fmaf(xrow[wave][d], wenc[d * HH + lane], hacc);
            hrow[wave][lane] = fmaxf(hacc, 0.f);
        }
        __syncthreads();
        if (valid) {
            float hgacc = 0.f;
            #pragma unroll 8
            for (int k = 0; k < HH; k++) hgacc = fmaf(hrow[wave][k], wgat[k * HH + lane], hgacc);
            hg[node * HH + lane] = hgacc;
            float ps = hgacc * avs[lane];
            float pd = hgacc * avd[lane];
            #pragma unroll
            for (int off = 32; off; off >>= 1) {
                ps += __shfl_xor(ps, off);
                pd += __shfl_xor(pd, off);
            }
            if (lane == 0) { s_src[node] = ps; s_dst[node] = pd; }
        }
        __syncthreads();
    }
}

// ---------- K3: segment max of scores over dst ----------
__global__ void k_edgemax(const int* __restrict__ src, const int* __restrict__ dst,
                          const float* __restrict__ s_src, const float* __restrict__ s_dst,
                          unsigned* __restrict__ m_enc) {
    int e = blockIdx.x * blockDim.x + threadIdx.x;
    if (e >= EE) return;
    int sv = src[e], dv = dst[e];
    float s = s_src[sv] + s_dst[dv];
    s = (s >= 0.f) ? s : 0.2f * s;        // leaky_relu 0.2
    atomicMax(&m_enc[dv], enc_f32(s));
}

// ---------- K4: denom = segment sum of exp(s - m) ----------
__global__ void k_edgesum(const int* __restrict__ src, const int* __restrict__ dst,
                          const float* __restrict__ s_src, const float* __restrict__ s_dst,
                          const unsigned* __restrict__ m_enc, float* __restrict__ denom) {
    int e = blockIdx.x * blockDim.x + threadIdx.x;
    if (e >= EE) return;
    int sv = src[e], dv = dst[e];
    float s = s_src[sv] + s_dst[dv];
    s = (s >= 0.f) ? s : 0.2f * s;
    float m = dec_f32(m_enc[dv]);
    atomicAdd(&denom[dv], expf(s - m));
}

// ---------- K5: agg[dst] += alpha * hg[src]  (wave per edge) ----------
__global__ __launch_bounds__(256) void k_agg(
        const int* __restrict__ src, const int* __restrict__ dst,
        const float* __restrict__ s_src, const float* __restrict__ s_dst,
        const unsigned* __restrict__ m_enc, const float* __restrict__ denom,
        const float* __restrict__ hg, float* __restrict__ agg) {
    int wave = threadIdx.x >> 6, lane = threadIdx.x & 63;
    int e = blockIdx.x * 4 + wave;
    if (e >= EE) return;
    int sv = src[e], dv = dst[e];
    float s = s_src[sv] + s_dst[dv];
    s = (s >= 0.f) ? s : 0.2f * s;
    float m = dec_f32(m_enc[dv]);
    float alpha = expf(s - m) / (denom[dv] + 1e-9f);
    atomicAdd(&agg[dv * HH + lane], alpha * hg[sv * HH + lane]);
}

// ---------- K6: xc = relu(agg); node head; p_src/p_dst partials for edge head ----------
// NOTE: p_dst aliases agg (safe: each node's row is read before being overwritten
// by the same wave), p_src aliases hg (hg is dead after K5). No __restrict__ here.
__global__ __launch_bounds__(256) void k_nodehead(
        const float* agg,
        const float* __restrict__ Wn1, const float* __restrict__ bn1,
        const float* __restrict__ Wn2, const float* __restrict__ bn2,
        const float* __restrict__ We1,
        float* p_src, float* p_dst, float* out_node) {
    __shared__ float wn1[HH * HH];    // 16 KB
    __shared__ float we1s[HH * HH];   // 16 KB (We1 rows 0..63   -> xc[src] part)
    __shared__ float we1d[HH * HH];   // 16 KB (We1 rows 64..127 -> xc[dst] part)
    __shared__ float wn2[HH * NCLS];
    __shared__ float xcs[4][HH];
    int tid = threadIdx.x;
    for (int i = tid; i < HH * HH; i += 256) {
        wn1[i]  = Wn1[i];
        we1s[i] = We1[i];
        we1d[i] = We1[HH * HH + i];
    }
    if (tid < HH * NCLS) wn2[tid] = Wn2[tid];
    __syncthreads();
    int wave = tid >> 6, lane = tid & 63;
    for (int base = blockIdx.x * 4; base < NN; base += gridDim.x * 4) {
        int node = base + wave;
        bool valid = node < NN;
        if (valid) xcs[wave][lane] = fmaxf(agg[node * HH + lane], 0.f);
        __syncthreads();
        if (valid) {
            float tn = bn1[lane], ps = 0.f, pd = 0.f;
            #pragma unroll 8
            for (int k = 0; k < HH; k++) {
                float xv = xcs[wave][k];
                tn = fmaf(xv, wn1[k * HH + lane], tn);
                ps = fmaf(xv, we1s[k * HH + lane], ps);
                pd = fmaf(xv, we1d[k * HH + lane], pd);
            }
            p_src[node * HH + lane] = ps;
            p_dst[node * HH + lane] = pd;
            tn = fmaxf(tn, 0.f);
            float l0 = tn * wn2[lane * NCLS + 0];
            float l1 = tn * wn2[lane * NCLS + 1];
            #pragma unroll
            for (int off = 32; off; off >>= 1) {
                l0 += __shfl_xor(l0, off);
                l1 += __shfl_xor(l1, off);
            }
            if (lane == 0) {
                out_node[node * NCLS + 0] = l0 + bn2[0];
                out_node[node * NCLS + 1] = l1 + bn2[1];
            }
        }
        __syncthreads();
    }
}

// ---------- K7: edge head: t1 = relu(p_src[s]+p_dst[d]+attr@We1_a+be1); logits ----------
__global__ __launch_bounds__(256) void k_edgehead(
        const int* __restrict__ src, const int* __restrict__ dst,
        const float* __restrict__ edge_attr,
        const float* __restrict__ p_src, const float* __restrict__ p_dst,
        const float* __restrict__ We1, const float* __restrict__ be1,
        const float* __restrict__ We2, const float* __restrict__ be2,
        float* __restrict__ out_edge) {
    int wave = threadIdx.x >> 6, lane = threadIdx.x & 63;
    int stride = gridDim.x * 4;
    for (int e = blockIdx.x * 4 + wave; e < EE; e += stride) {
        int sv = src[e], dv = dst[e];
        float t = p_src[sv * HH + lane] + p_dst[dv * HH + lane] + be1[lane];
        #pragma unroll
        for (int d = 0; d < DEA; d++)
            t = fmaf(edge_attr[e * DEA + d], We1[(2 * HH + d) * HH + lane], t);
        t = fmaxf(t, 0.f);
        float l0 = t * We2[lane * NCLS + 0];
        float l1 = t * We2[lane * NCLS + 1];
        #pragma unroll
        for (int off = 32; off; off >>= 1) {
            l0 += __shfl_xor(l0, off);
            l1 += __shfl_xor(l1, off);
        }
        if (lane == 0) {
            out_edge[e * NCLS + 0] = l0 + be2[0];
            out_edge[e * NCLS + 1] = l1 + be2[1];
        }
    }
}

extern "C" void kernel_launch(void* const* d_in, const int* in_sizes, int n_in,
                              void* d_out, int out_size, void* d_ws, size_t ws_size,
                              hipStream_t stream) {
    const float* x      = (const float*)d_in[0];
    const int*   ei     = (const int*)  d_in[1];
    const float* attr   = (const float*)d_in[2];
    const float* W_enc  = (const float*)d_in[3];
    const float* b_enc  = (const float*)d_in[4];
    const float* W_gat  = (const float*)d_in[5];
    const float* a_src  = (const float*)d_in[6];
    const float* a_dst  = (const float*)d_in[7];
    const float* Wn1    = (const float*)d_in[8];
    const float* bn1    = (const float*)d_in[9];
    const float* Wn2    = (const float*)d_in[10];
    const float* bn2    = (const float*)d_in[11];
    const float* We1    = (const float*)d_in[12];
    const float* be1    = (const float*)d_in[13];
    const float* We2    = (const float*)d_in[14];
    const float* be2    = (const float*)d_in[15];
    float* out = (float*)d_out;
    float* ws  = (float*)d_ws;

    // workspace layout (floats):
    float*    hg_psrc = ws;                        // [N*H] hg, later p_src
    float*    agg_pd  = ws + (size_t)NN * HH;      // [N*H] agg, later p_dst
    float*    ssrc    = ws + (size_t)2 * NN * HH;  // [N]
    float*    sdst    = ssrc + NN;                 // [N]
    unsigned* menc    = (unsigned*)(sdst + NN);    // [N]
    float*    denom   = sdst + 2 * NN;             // [N]

    const int* srcp = ei;
    const int* dstp = ei + EE;

    k_init    <<<2048, 256, 0, stream>>>(agg_pd, menc, denom);
    k_encode  <<<2048, 256, 0, stream>>>(x, W_enc, b_enc, W_gat, a_src, a_dst,
                                         hg_psrc, ssrc, sdst);
    k_edgemax <<<(EE + 255) / 256, 256, 0, stream>>>(srcp, dstp, ssrc, sdst, menc);
    k_edgesum <<<(EE + 255) / 256, 256, 0, stream>>>(srcp, dstp, ssrc, sdst, menc, denom);
    k_agg     <<<(EE + 3) / 4, 256, 0, stream>>>(srcp, dstp, ssrc, sdst, menc, denom,
                                                 hg_psrc, agg_pd);
    k_nodehead<<<2048, 256, 0, stream>>>(agg_pd, Wn1, bn1, Wn2, bn2, We1,
                                         hg_psrc /*p_src*/, agg_pd /*p_dst*/, out);
    k_edgehead<<<4096, 256, 0, stream>>>(srcp, dstp, attr, hg_psrc, agg_pd,
                                         We1, be1, We2, be2, out + (size_t)NN * NCLS);
}

// Round 2
// 780.594 us; speedup vs baseline: 1.2665x; 1.2665x over previous
//
#include <hip/hip_runtime.h>
#include <hip/hip_bf16.h>

#define NN   100000
#define EE   1600000
#define DIN  128
#define HH   64
#define DEA  8
#define NCLS 2
#define NBLK ((NN + 255) / 256)   // 391 scan blocks

// ---------- K1: zero the dst-degree histogram ----------
__global__ void k_init(int* counts) {
    int i = blockIdx.x * blockDim.x + threadIdx.x;
    if (i < NN) counts[i] = 0;
}

// ---------- K2: h = relu(x@W_enc+b); hg = h@W_gat; s_src/s_dst = hg . a ----------
__global__ __launch_bounds__(256) void k_encode(
        const float* __restrict__ x,
        const float* __restrict__ W_enc, const float* __restrict__ b_enc,
        const float* __restrict__ W_gat,
        const float* __restrict__ a_src, const float* __restrict__ a_dst,
        float* __restrict__ hg, float* __restrict__ s_src, float* __restrict__ s_dst) {
    __shared__ float wenc[DIN * HH];   // 32 KB
    __shared__ float wgat[HH * HH];    // 16 KB
    __shared__ float benc[HH], avs[HH], avd[HH];
    __shared__ float xrow[4][DIN];
    __shared__ float hrow[4][HH];
    int tid = threadIdx.x;
    for (int i = tid; i < DIN * HH; i += 256) wenc[i] = W_enc[i];
    for (int i = tid; i < HH * HH; i += 256) wgat[i] = W_gat[i];
    if (tid < HH) { benc[tid] = b_enc[tid]; avs[tid] = a_src[tid]; avd[tid] = a_dst[tid]; }
    __syncthreads();
    int wave = tid >> 6, lane = tid & 63;
    for (int base = blockIdx.x * 4; base < NN; base += gridDim.x * 4) {
        int node = base + wave;
        bool valid = node < NN;
        if (valid) {
            xrow[wave][lane]      = x[node * DIN + lane];
            xrow[wave][lane + 64] = x[node * DIN + 64 + lane];
        }
        __syncthreads();
        if (valid) {
            float hacc = benc[lane];
            #pragma unroll 8
            for (int d = 0; d < DIN; d++) hacc = fmaf(xrow[wave][d], wenc[d * HH + lane], hacc);
            hrow[wave][lane] = fmaxf(hacc, 0.f);
        }
        __syncthreads();
        if (valid) {
            float hgacc = 0.f;
            #pragma unroll 8
            for (int k = 0; k < HH; k++) hgacc = fmaf(hrow[wave][k], wgat[k * HH + lane], hgacc);
            hg[node * HH + lane] = hgacc;
            float ps = hgacc * avs[lane];
            float pd = hgacc * avd[lane];
            #pragma unroll
            for (int off = 32; off; off >>= 1) {
                ps += __shfl_xor(ps, off);
                pd += __shfl_xor(pd, off);
            }
            if (lane == 0) { s_src[node] = ps; s_dst[node] = pd; }
        }
        __syncthreads();
    }
}

// ---------- K3: histogram of dst ----------
__global__ void k_hist(const int* __restrict__ dst, int* __restrict__ counts) {
    int e = blockIdx.x * blockDim.x + threadIdx.x;
    if (e < EE) atomicAdd(&counts[dst[e]], 1);
}

// ---------- K4a: per-block totals ----------
__global__ void k_scanA(const int* __restrict__ counts, int* __restrict__ bsum) {
    __shared__ int sm[256];
    int i = blockIdx.x * 256 + threadIdx.x;
    sm[threadIdx.x] = (i < NN) ? counts[i] : 0;
    __syncthreads();
    for (int s = 128; s; s >>= 1) {
        if (threadIdx.x < s) sm[threadIdx.x] += sm[threadIdx.x + s];
        __syncthreads();
    }
    if (threadIdx.x == 0) bsum[blockIdx.x] = sm[0];
}

// ---------- K4b: scan block totals (1 block, 512 threads; NBLK=391 < 512) ----------
__global__ void k_scanB(const int* __restrict__ bsum, int* __restrict__ boff) {
    __shared__ int sm[512];
    int t = threadIdx.x;
    int v = (t < NBLK) ? bsum[t] : 0;
    sm[t] = v;
    __syncthreads();
    for (int s = 1; s < 512; s <<= 1) {
        int add = (t >= s) ? sm[t - s] : 0;
        __syncthreads();
        sm[t] += add;
        __syncthreads();
    }
    if (t < NBLK) boff[t] = sm[t] - v;   // exclusive prefix of block totals
}

// ---------- K4c: full exclusive scan -> cursor (scatter turns it into row-end) ----------
__global__ void k_scanC(const int* __restrict__ counts, const int* __restrict__ boff,
                        int* __restrict__ cursor) {
    __shared__ int sm[256];
    int b = blockIdx.x, t = threadIdx.x;
    int i = b * 256 + t;
    int v = (i < NN) ? counts[i] : 0;
    sm[t] = v;
    __syncthreads();
    for (int s = 1; s < 256; s <<= 1) {
        int add = (t >= s) ? sm[t - s] : 0;
        __syncthreads();
        sm[t] += add;
        __syncthreads();
    }
    if (i < NN) cursor[i] = boff[b] + sm[t] - v;   // exclusive start
}

// ---------- K5: scatter src indices into CSR order (cursor becomes row-end) ----------
__global__ void k_scatter(const int* __restrict__ src, const int* __restrict__ dst,
                          int* cursor, int* __restrict__ csr_src) {
    int e = blockIdx.x * blockDim.x + threadIdx.x;
    if (e >= EE) return;
    int pos = atomicAdd(&cursor[dst[e]], 1);
    csr_src[pos] = src[e];
}

// ---------- K6: per-dst-node softmax + aggregation, no atomics ----------
__global__ __launch_bounds__(256) void k_aggcsr(
        const int* __restrict__ csr_src, const int* __restrict__ cursor_end,
        const int* __restrict__ counts,
        const float* __restrict__ s_src, const float* __restrict__ s_dst,
        const float* __restrict__ hg, float* __restrict__ agg) {
    int wave = threadIdx.x >> 6, lane = threadIdx.x & 63;
    int node = blockIdx.x * 4 + wave;
    if (node >= NN) return;
    int deg = counts[node];
    if (deg == 0) { agg[(size_t)node * HH + lane] = 0.f; return; }
    int rs = cursor_end[node] - deg;
    float sd = s_dst[node];
    // pass 1: segment max (keep first chunk's sv/score in regs — deg<=64 is the common case)
    float m = -INFINITY;
    int sv0 = 0; float sc0 = -INFINITY;
    for (int base = 0; base < deg; base += 64) {
        int i = base + lane;
        int sv = 0; float sc = -INFINITY;
        if (i < deg) {
            sv = csr_src[rs + i];
            float s = s_src[sv] + sd;
            sc = (s >= 0.f) ? s : 0.2f * s;        // leaky_relu 0.2
        }
        if (base == 0) { sv0 = sv; sc0 = sc; }
        m = fmaxf(m, sc);
    }
    #pragma unroll
    for (int off = 32; off; off >>= 1) m = fmaxf(m, __shfl_xor(m, off));
    // pass 2: unnormalized accumulate; divide once at the end
    float denom = 0.f, acc = 0.f;
    for (int base = 0; base < deg; base += 64) {
        int i = base + lane;
        int sv; float sc;
        if (base == 0) { sv = sv0; sc = sc0; }
        else {
            sv = 0; sc = -INFINITY;
            if (i < deg) {
                sv = csr_src[rs + i];
                float s = s_src[sv] + sd;
                sc = (s >= 0.f) ? s : 0.2f * s;
            }
        }
        float ex = (i < deg) ? __expf(sc - m) : 0.f;
        denom += ex;
        int cn = min(deg - base, 64);
        for (int j = 0; j < cn; j++) {
            int   svj = __shfl(sv, j);
            float exj = __shfl(ex, j);
            acc = fmaf(exj, hg[(size_t)svj * HH + lane], acc);
        }
    }
    #pragma unroll
    for (int off = 32; off; off >>= 1) denom += __shfl_xor(denom, off);
    agg[(size_t)node * HH + lane] = acc / (denom + 1e-9f);
}

// ---------- K7: xc = relu(agg); node head; p_src/p_dst partials for edge head ----------
// NOTE: p_dst aliases agg (row read before overwrite by same wave), p_src aliases hg.
__global__ __launch_bounds__(256) void k_nodehead(
        const float* agg,
        const float* __restrict__ Wn1, const float* __restrict__ bn1,
        const float* __restrict__ Wn2, const float* __restrict__ bn2,
        const float* __restrict__ We1,
        float* p_src, float* p_dst, float* out_node) {
    __shared__ float wn1[HH * HH];
    __shared__ float we1s[HH * HH];
    __shared__ float we1d[HH * HH];
    __shared__ float wn2[HH * NCLS];
    __shared__ float xcs[4][HH];
    int tid = threadIdx.x;
    for (int i = tid; i < HH * HH; i += 256) {
        wn1[i]  = Wn1[i];
        we1s[i] = We1[i];
        we1d[i] = We1[HH * HH + i];
    }
    if (tid < HH * NCLS) wn2[tid] = Wn2[tid];
    __syncthreads();
    int wave = tid >> 6, lane = tid & 63;
    for (int base = blockIdx.x * 4; base < NN; base += gridDim.x * 4) {
        int node = base + wave;
        bool valid = node < NN;
        if (valid) xcs[wave][lane] = fmaxf(agg[(size_t)node * HH + lane], 0.f);
        __syncthreads();
        if (valid) {
            float tn = bn1[lane], ps = 0.f, pd = 0.f;
            #pragma unroll 8
            for (int k = 0; k < HH; k++) {
                float xv = xcs[wave][k];
                tn = fmaf(xv, wn1[k * HH + lane], tn);
                ps = fmaf(xv, we1s[k * HH + lane], ps);
                pd = fmaf(xv, we1d[k * HH + lane], pd);
            }
            p_src[(size_t)node * HH + lane] = ps;
            p_dst[(size_t)node * HH + lane] = pd;
            tn = fmaxf(tn, 0.f);
            float l0 = tn * wn2[lane * NCLS + 0];
            float l1 = tn * wn2[lane * NCLS + 1];
            #pragma unroll
            for (int off = 32; off; off >>= 1) {
                l0 += __shfl_xor(l0, off);
                l1 += __shfl_xor(l1, off);
            }
            if (lane == 0) {
                out_node[node * NCLS + 0] = l0 + bn2[0];
                out_node[node * NCLS + 1] = l1 + bn2[1];
            }
        }
        __syncthreads();
    }
}

// ---------- K8: edge head ----------
__global__ __launch_bounds__(256) void k_edgehead(
        const int* __restrict__ src, const int* __restrict__ dst,
        const float* __restrict__ edge_attr,
        const float* __restrict__ p_src, const float* __restrict__ p_dst,
        const float* __restrict__ We1, const float* __restrict__ be1,
        const float* __restrict__ We2, const float* __restrict__ be2,
        float* __restrict__ out_edge) {
    int wave = threadIdx.x >> 6, lane = threadIdx.x & 63;
    int stride = gridDim.x * 4;
    for (int e = blockIdx.x * 4 + wave; e < EE; e += stride) {
        int sv = src[e], dv = dst[e];
        float t = p_src[(size_t)sv * HH + lane] + p_dst[(size_t)dv * HH + lane] + be1[lane];
        #pragma unroll
        for (int d = 0; d < DEA; d++)
            t = fmaf(edge_attr[e * DEA + d], We1[(2 * HH + d) * HH + lane], t);
        t = fmaxf(t, 0.f);
        float l0 = t * We2[lane * NCLS + 0];
        float l1 = t * We2[lane * NCLS + 1];
        #pragma unroll
        for (int off = 32; off; off >>= 1) {
            l0 += __shfl_xor(l0, off);
            l1 += __shfl_xor(l1, off);
        }
        if (lane == 0) {
            out_edge[e * NCLS + 0] = l0 + be2[0];
            out_edge[e * NCLS + 1] = l1 + be2[1];
        }
    }
}

extern "C" void kernel_launch(void* const* d_in, const int* in_sizes, int n_in,
                              void* d_out, int out_size, void* d_ws, size_t ws_size,
                              hipStream_t stream) {
    const float* x      = (const float*)d_in[0];
    const int*   ei     = (const int*)  d_in[1];
    const float* attr   = (const float*)d_in[2];
    const float* W_enc  = (const float*)d_in[3];
    const float* b_enc  = (const float*)d_in[4];
    const float* W_gat  = (const float*)d_in[5];
    const float* a_src  = (const float*)d_in[6];
    const float* a_dst  = (const float*)d_in[7];
    const float* Wn1    = (const float*)d_in[8];
    const float* bn1    = (const float*)d_in[9];
    const float* Wn2    = (const float*)d_in[10];
    const float* bn2    = (const float*)d_in[11];
    const float* We1    = (const float*)d_in[12];
    const float* be1    = (const float*)d_in[13];
    const float* We2    = (const float*)d_in[14];
    const float* be2    = (const float*)d_in[15];
    float* out = (float*)d_out;
    float* ws  = (float*)d_ws;

    // workspace layout (4-byte units), total ~59.3 MB:
    float* hg_psrc = ws;                               // [N*H] hg, later p_src
    float* agg_pd  = ws + (size_t)NN * HH;             // [N*H] agg, later p_dst
    float* ssrc    = ws + (size_t)2 * NN * HH;         // [N]
    float* sdst    = ssrc + NN;                        // [N]
    int*   counts  = (int*)(sdst + NN);                // [N]
    int*   cursor  = counts + NN;                      // [N] exclusive start -> row end
    int*   csr_src = cursor + NN;                      // [E]
    int*   bsum    = csr_src + EE;                     // [NBLK]
    int*   boff    = bsum + 512;                       // [NBLK]

    const int* srcp = ei;
    const int* dstp = ei + EE;

    k_init    <<<(NN + 255) / 256, 256, 0, stream>>>(counts);
    k_encode  <<<2048, 256, 0, stream>>>(x, W_enc, b_enc, W_gat, a_src, a_dst,
                                         hg_psrc, ssrc, sdst);
    k_hist    <<<(EE + 255) / 256, 256, 0, stream>>>(dstp, counts);
    k_scanA   <<<NBLK, 256, 0, stream>>>(counts, bsum);
    k_scanB   <<<1, 512, 0, stream>>>(bsum, boff);
    k_scanC   <<<NBLK, 256, 0, stream>>>(counts, boff, cursor);
    k_scatter <<<(EE + 255) / 256, 256, 0, stream>>>(srcp, dstp, cursor, csr_src);
    k_aggcsr  <<<(NN + 3) / 4, 256, 0, stream>>>(csr_src, cursor, counts,
                                                 ssrc, sdst, hg_psrc, agg_pd);
    k_nodehead<<<2048, 256, 0, stream>>>(agg_pd, Wn1, bn1, Wn2, bn2, We1,
                                         hg_psrc /*p_src*/, agg_pd /*p_dst*/, out);
    k_edgehead<<<4096, 256, 0, stream>>>(srcp, dstp, attr, hg_psrc, agg_pd,
                                         We1, be1, We2, be2, out + (size_t)NN * NCLS);
}

// Round 3
// 763.781 us; speedup vs baseline: 1.2943x; 1.0220x over previous
//
#include <hip/hip_runtime.h>
#include <hip/hip_bf16.h>

#define NN   100000
#define EE   1600000
#define DIN  128
#define HH   64
#define DEA  8
#define NCLS 2
#define NBLK ((NN + 255) / 256)   // 391 scan blocks

typedef __hip_bfloat16 bf16;

// ---------- K2: h = relu(x@W_enc+b); hg = h@W_gat (bf16); s_src/s_dst = hg . a ----------
__global__ __launch_bounds__(256) void k_encode(
        const float* __restrict__ x,
        const float* __restrict__ W_enc, const float* __restrict__ b_enc,
        const float* __restrict__ W_gat,
        const float* __restrict__ a_src, const float* __restrict__ a_dst,
        bf16* __restrict__ hg, float* __restrict__ s_src, float* __restrict__ s_dst) {
    __shared__ float wenc[DIN * HH];   // 32 KB
    __shared__ float wgat[HH * HH];    // 16 KB
    __shared__ float benc[HH], avs[HH], avd[HH];
    __shared__ float xrow[4][DIN];
    __shared__ float hrow[4][HH];
    int tid = threadIdx.x;
    for (int i = tid; i < DIN * HH; i += 256) wenc[i] = W_enc[i];
    for (int i = tid; i < HH * HH; i += 256) wgat[i] = W_gat[i];
    if (tid < HH) { benc[tid] = b_enc[tid]; avs[tid] = a_src[tid]; avd[tid] = a_dst[tid]; }
    __syncthreads();
    int wave = tid >> 6, lane = tid & 63;
    for (int base = blockIdx.x * 4; base < NN; base += gridDim.x * 4) {
        int node = base + wave;
        bool valid = node < NN;
        if (valid) {
            xrow[wave][lane]      = x[node * DIN + lane];
            xrow[wave][lane + 64] = x[node * DIN + 64 + lane];
        }
        __syncthreads();
        if (valid) {
            float hacc = benc[lane];
            #pragma unroll 8
            for (int d = 0; d < DIN; d++) hacc = fmaf(xrow[wave][d], wenc[d * HH + lane], hacc);
            hrow[wave][lane] = fmaxf(hacc, 0.f);
        }
        __syncthreads();
        if (valid) {
            float hgacc = 0.f;
            #pragma unroll 8
            for (int k = 0; k < HH; k++) hgacc = fmaf(hrow[wave][k], wgat[k * HH + lane], hgacc);
            hg[(size_t)node * HH + lane] = __float2bfloat16(hgacc);
            float ps = hgacc * avs[lane];
            float pd = hgacc * avd[lane];
            #pragma unroll
            for (int off = 32; off; off >>= 1) {
                ps += __shfl_xor(ps, off);
                pd += __shfl_xor(pd, off);
            }
            if (lane == 0) { s_src[node] = ps; s_dst[node] = pd; }
        }
        __syncthreads();
    }
}

// ---------- K3: histogram of dst ----------
__global__ void k_hist(const int* __restrict__ dst, int* __restrict__ counts) {
    int e = blockIdx.x * blockDim.x + threadIdx.x;
    if (e < EE) atomicAdd(&counts[dst[e]], 1);
}

// ---------- K4a: per-block totals ----------
__global__ void k_scanA(const int* __restrict__ counts, int* __restrict__ bsum) {
    __shared__ int sm[256];
    int i = blockIdx.x * 256 + threadIdx.x;
    sm[threadIdx.x] = (i < NN) ? counts[i] : 0;
    __syncthreads();
    for (int s = 128; s; s >>= 1) {
        if (threadIdx.x < s) sm[threadIdx.x] += sm[threadIdx.x + s];
        __syncthreads();
    }
    if (threadIdx.x == 0) bsum[blockIdx.x] = sm[0];
}

// ---------- K4b: scan block totals (1 block, 512 threads; NBLK=391 < 512) ----------
__global__ void k_scanB(const int* __restrict__ bsum, int* __restrict__ boff) {
    __shared__ int sm[512];
    int t = threadIdx.x;
    int v = (t < NBLK) ? bsum[t] : 0;
    sm[t] = v;
    __syncthreads();
    for (int s = 1; s < 512; s <<= 1) {
        int add = (t >= s) ? sm[t - s] : 0;
        __syncthreads();
        sm[t] += add;
        __syncthreads();
    }
    if (t < NBLK) boff[t] = sm[t] - v;   // exclusive prefix of block totals
}

// ---------- K4c: full exclusive scan -> cursor (scatter turns it into row-end) ----------
__global__ void k_scanC(const int* __restrict__ counts, const int* __restrict__ boff,
                        int* __restrict__ cursor) {
    __shared__ int sm[256];
    int b = blockIdx.x, t = threadIdx.x;
    int i = b * 256 + t;
    int v = (i < NN) ? counts[i] : 0;
    sm[t] = v;
    __syncthreads();
    for (int s = 1; s < 256; s <<= 1) {
        int add = (t >= s) ? sm[t - s] : 0;
        __syncthreads();
        sm[t] += add;
        __syncthreads();
    }
    if (i < NN) cursor[i] = boff[b] + sm[t] - v;   // exclusive start
}

// ---------- K5: scatter src indices into CSR order (cursor becomes row-end) ----------
__global__ void k_scatter(const int* __restrict__ src, const int* __restrict__ dst,
                          int* cursor, int* __restrict__ csr_src) {
    int e = blockIdx.x * blockDim.x + threadIdx.x;
    if (e >= EE) return;
    int pos = atomicAdd(&cursor[dst[e]], 1);
    csr_src[pos] = src[e];
}

// ---------- K6: per-dst-node softmax + aggregation (single pass, m=0 shift) ----------
// softmax is shift-invariant; scores are O(+-8) so exp() cannot overflow in f32.
__global__ __launch_bounds__(256) void k_aggcsr(
        const int* __restrict__ csr_src, const int* __restrict__ cursor_end,
        const int* __restrict__ counts,
        const float* __restrict__ s_src, const float* __restrict__ s_dst,
        const bf16* __restrict__ hg, float* __restrict__ agg) {
    int wave = threadIdx.x >> 6, lane = threadIdx.x & 63;
    int node = blockIdx.x * 4 + wave;
    if (node >= NN) return;
    int deg = counts[node];
    if (deg == 0) { agg[(size_t)node * HH + lane] = 0.f; return; }
    int rs = cursor_end[node] - deg;
    float sd = s_dst[node];
    float denom = 0.f, acc = 0.f;
    for (int base = 0; base < deg; base += 64) {
        int i = base + lane;
        int sv = 0; float ex = 0.f;
        if (i < deg) {
            sv = csr_src[rs + i];
            float s = s_src[sv] + sd;
            s = (s >= 0.f) ? s : 0.2f * s;        // leaky_relu 0.2
            ex = __expf(s);
        }
        denom += ex;
        int cn = min(deg - base, 64);
        for (int j = 0; j < cn; j++) {
            int   svj = __shfl(sv, j);
            float exj = __shfl(ex, j);
            acc = fmaf(exj, __bfloat162float(hg[(size_t)svj * HH + lane]), acc);
        }
    }
    #pragma unroll
    for (int off = 32; off; off >>= 1) denom += __shfl_xor(denom, off);
    agg[(size_t)node * HH + lane] = acc / (denom + 1e-9f);
}

// ---------- K7: xc = relu(agg); node head; bf16 p_src/p_dst partials ----------
// p_src aliases hg (bf16, same indexing; hg dead after K6). p_dst is separate.
__global__ __launch_bounds__(256) void k_nodehead(
        const float* __restrict__ agg,
        const float* __restrict__ Wn1, const float* __restrict__ bn1,
        const float* __restrict__ Wn2, const float* __restrict__ bn2,
        const float* __restrict__ We1,
        bf16* __restrict__ p_src, bf16* __restrict__ p_dst, float* __restrict__ out_node) {
    __shared__ float wn1[HH * HH];
    __shared__ float we1s[HH * HH];
    __shared__ float we1d[HH * HH];
    __shared__ float wn2[HH * NCLS];
    __shared__ float xcs[4][HH];
    int tid = threadIdx.x;
    for (int i = tid; i < HH * HH; i += 256) {
        wn1[i]  = Wn1[i];
        we1s[i] = We1[i];
        we1d[i] = We1[HH * HH + i];
    }
    if (tid < HH * NCLS) wn2[tid] = Wn2[tid];
    __syncthreads();
    int wave = tid >> 6, lane = tid & 63;
    for (int base = blockIdx.x * 4; base < NN; base += gridDim.x * 4) {
        int node = base + wave;
        bool valid = node < NN;
        if (valid) xcs[wave][lane] = fmaxf(agg[(size_t)node * HH + lane], 0.f);
        __syncthreads();
        if (valid) {
            float tn = bn1[lane], ps = 0.f, pd = 0.f;
            #pragma unroll 8
            for (int k = 0; k < HH; k++) {
                float xv = xcs[wave][k];
                tn = fmaf(xv, wn1[k * HH + lane], tn);
                ps = fmaf(xv, we1s[k * HH + lane], ps);
                pd = fmaf(xv, we1d[k * HH + lane], pd);
            }
            p_src[(size_t)node * HH + lane] = __float2bfloat16(ps);
            p_dst[(size_t)node * HH + lane] = __float2bfloat16(pd);
            tn = fmaxf(tn, 0.f);
            float l0 = tn * wn2[lane * NCLS + 0];
            float l1 = tn * wn2[lane * NCLS + 1];
            #pragma unroll
            for (int off = 32; off; off >>= 1) {
                l0 += __shfl_xor(l0, off);
                l1 += __shfl_xor(l1, off);
            }
            if (lane == 0) {
                out_node[node * NCLS + 0] = l0 + bn2[0];
                out_node[node * NCLS + 1] = l1 + bn2[1];
            }
        }
        __syncthreads();
    }
}

// ---------- K8: edge head (bf16 gathers) ----------
__global__ __launch_bounds__(256) void k_edgehead(
        const int* __restrict__ src, const int* __restrict__ dst,
        const float* __restrict__ edge_attr,
        const bf16* __restrict__ p_src, const bf16* __restrict__ p_dst,
        const float* __restrict__ We1, const float* __restrict__ be1,
        const float* __restrict__ We2, const float* __restrict__ be2,
        float* __restrict__ out_edge) {
    int wave = threadIdx.x >> 6, lane = threadIdx.x & 63;
    int stride = gridDim.x * 4;
    for (int e = blockIdx.x * 4 + wave; e < EE; e += stride) {
        int sv = src[e], dv = dst[e];
        float t = __bfloat162float(p_src[(size_t)sv * HH + lane])
                + __bfloat162float(p_dst[(size_t)dv * HH + lane]) + be1[lane];
        #pragma unroll
        for (int d = 0; d < DEA; d++)
            t = fmaf(edge_attr[e * DEA + d], We1[(2 * HH + d) * HH + lane], t);
        t = fmaxf(t, 0.f);
        float l0 = t * We2[lane * NCLS + 0];
        float l1 = t * We2[lane * NCLS + 1];
        #pragma unroll
        for (int off = 32; off; off >>= 1) {
            l0 += __shfl_xor(l0, off);
            l1 += __shfl_xor(l1, off);
        }
        if (lane == 0) {
            *(float2*)&out_edge[(size_t)e * NCLS] = make_float2(l0 + be2[0], l1 + be2[1]);
        }
    }
}

extern "C" void kernel_launch(void* const* d_in, const int* in_sizes, int n_in,
                              void* d_out, int out_size, void* d_ws, size_t ws_size,
                              hipStream_t stream) {
    const float* x      = (const float*)d_in[0];
    const int*   ei     = (const int*)  d_in[1];
    const float* attr   = (const float*)d_in[2];
    const float* W_enc  = (const float*)d_in[3];
    const float* b_enc  = (const float*)d_in[4];
    const float* W_gat  = (const float*)d_in[5];
    const float* a_src  = (const float*)d_in[6];
    const float* a_dst  = (const float*)d_in[7];
    const float* Wn1    = (const float*)d_in[8];
    const float* bn1    = (const float*)d_in[9];
    const float* Wn2    = (const float*)d_in[10];
    const float* bn2    = (const float*)d_in[11];
    const float* We1    = (const float*)d_in[12];
    const float* be1    = (const float*)d_in[13];
    const float* We2    = (const float*)d_in[14];
    const float* be2    = (const float*)d_in[15];
    float* out = (float*)d_out;
    float* ws  = (float*)d_ws;

    // workspace layout (float units), total ~59 MB:
    bf16*  hg_psrc = (bf16*)ws;                        // [N*H] bf16: hg, later p_src
    float* agg     = ws + (size_t)NN * 32;             // [N*H] f32
    bf16*  p_dst   = (bf16*)(ws + (size_t)NN * 96);    // [N*H] bf16
    float* ssrc    = ws + (size_t)NN * 128;            // [N]
    float* sdst    = ssrc + NN;                        // [N]
    int*   counts  = (int*)(sdst + NN);                // [N]
    int*   cursor  = counts + NN;                      // [N] exclusive start -> row end
    int*   csr_src = cursor + NN;                      // [E]
    int*   bsum    = csr_src + EE;                     // [NBLK]
    int*   boff    = bsum + 512;                       // [NBLK]

    const int* srcp = ei;
    const int* dstp = ei + EE;

    hipMemsetAsync(counts, 0, NN * sizeof(int), stream);
    k_encode  <<<2048, 256, 0, stream>>>(x, W_enc, b_enc, W_gat, a_src, a_dst,
                                         hg_psrc, ssrc, sdst);
    k_hist    <<<(EE + 255) / 256, 256, 0, stream>>>(dstp, counts);
    k_scanA   <<<NBLK, 256, 0, stream>>>(counts, bsum);
    k_scanB   <<<1, 512, 0, stream>>>(bsum, boff);
    k_scanC   <<<NBLK, 256, 0, stream>>>(counts, boff, cursor);
    k_scatter <<<(EE + 255) / 256, 256, 0, stream>>>(srcp, dstp, cursor, csr_src);
    k_aggcsr  <<<(NN + 3) / 4, 256, 0, stream>>>(csr_src, cursor, counts,
                                                 ssrc, sdst, hg_psrc, agg);
    k_nodehead<<<2048, 256, 0, stream>>>(agg, Wn1, bn1, Wn2, bn2, We1,
                                         hg_psrc /*p_src*/, p_dst, out);
    k_edgehead<<<4096, 256, 0, stream>>>(srcp, dstp, attr, hg_psrc, p_dst,
                                         We1, be1, We2, be2, out + (size_t)NN * NCLS);
}

// Round 4
// 616.344 us; speedup vs baseline: 1.6040x; 1.2392x over previous
//
#include <hip/hip_runtime.h>
#include <hip/hip_bf16.h>

#define NN   100000
#define EE   1600000
#define DIN  128
#define HH   64
#define DEA  8
#define NCLS 2
#define NBLK ((NN + 255) / 256)   // 391 scan blocks

typedef __hip_bfloat16 bf16;

__device__ __forceinline__ float bf2f(unsigned short u) {
    union { unsigned i; float f; } v; v.i = ((unsigned)u) << 16; return v.f;
}
// unpack uint = two packed bf16 (lo = low 16 bits, hi = high 16 bits)
__device__ __forceinline__ void bf2x(unsigned u, float& lo, float& hi) {
    union { unsigned i; float f; } a, b;
    a.i = u << 16; b.i = u & 0xffff0000u;
    lo = a.f; hi = b.f;
}

// ---------- K2: h = relu(x@W_enc+b); hg = h@W_gat (bf16); s_src/s_dst = hg . a ----------
__global__ __launch_bounds__(256) void k_encode(
        const float* __restrict__ x,
        const float* __restrict__ W_enc, const float* __restrict__ b_enc,
        const float* __restrict__ W_gat,
        const float* __restrict__ a_src, const float* __restrict__ a_dst,
        bf16* __restrict__ hg, float* __restrict__ s_src, float* __restrict__ s_dst) {
    __shared__ float wenc[DIN * HH];   // 32 KB
    __shared__ float wgat[HH * HH];    // 16 KB
    __shared__ float benc[HH], avs[HH], avd[HH];
    __shared__ float xrow[4][DIN];
    __shared__ float hrow[4][HH];
    int tid = threadIdx.x;
    for (int i = tid; i < DIN * HH; i += 256) wenc[i] = W_enc[i];
    for (int i = tid; i < HH * HH; i += 256) wgat[i] = W_gat[i];
    if (tid < HH) { benc[tid] = b_enc[tid]; avs[tid] = a_src[tid]; avd[tid] = a_dst[tid]; }
    __syncthreads();
    int wave = tid >> 6, lane = tid & 63;
    for (int base = blockIdx.x * 4; base < NN; base += gridDim.x * 4) {
        int node = base + wave;
        bool valid = node < NN;
        if (valid) {
            xrow[wave][lane]      = x[node * DIN + lane];
            xrow[wave][lane + 64] = x[node * DIN + 64 + lane];
        }
        __syncthreads();
        if (valid) {
            float hacc = benc[lane];
            #pragma unroll 8
            for (int d = 0; d < DIN; d++) hacc = fmaf(xrow[wave][d], wenc[d * HH + lane], hacc);
            hrow[wave][lane] = fmaxf(hacc, 0.f);
        }
        __syncthreads();
        if (valid) {
            float hgacc = 0.f;
            #pragma unroll 8
            for (int k = 0; k < HH; k++) hgacc = fmaf(hrow[wave][k], wgat[k * HH + lane], hgacc);
            hg[(size_t)node * HH + lane] = __float2bfloat16(hgacc);
            float ps = hgacc * avs[lane];
            float pd = hgacc * avd[lane];
            #pragma unroll
            for (int off = 32; off; off >>= 1) {
                ps += __shfl_xor(ps, off);
                pd += __shfl_xor(pd, off);
            }
            if (lane == 0) { s_src[node] = ps; s_dst[node] = pd; }
        }
        __syncthreads();
    }
}

// ---------- K3: histogram of dst ----------
__global__ void k_hist(const int* __restrict__ dst, int* __restrict__ counts) {
    int e = blockIdx.x * blockDim.x + threadIdx.x;
    if (e < EE) atomicAdd(&counts[dst[e]], 1);
}

// ---------- K4a: per-block totals ----------
__global__ void k_scanA(const int* __restrict__ counts, int* __restrict__ bsum) {
    __shared__ int sm[256];
    int i = blockIdx.x * 256 + threadIdx.x;
    sm[threadIdx.x] = (i < NN) ? counts[i] : 0;
    __syncthreads();
    for (int s = 128; s; s >>= 1) {
        if (threadIdx.x < s) sm[threadIdx.x] += sm[threadIdx.x + s];
        __syncthreads();
    }
    if (threadIdx.x == 0) bsum[blockIdx.x] = sm[0];
}

// ---------- K4b: scan block totals (1 block, 512 threads; NBLK=391 < 512) ----------
__global__ void k_scanB(const int* __restrict__ bsum, int* __restrict__ boff) {
    __shared__ int sm[512];
    int t = threadIdx.x;
    int v = (t < NBLK) ? bsum[t] : 0;
    sm[t] = v;
    __syncthreads();
    for (int s = 1; s < 512; s <<= 1) {
        int add = (t >= s) ? sm[t - s] : 0;
        __syncthreads();
        sm[t] += add;
        __syncthreads();
    }
    if (t < NBLK) boff[t] = sm[t] - v;   // exclusive prefix of block totals
}

// ---------- K4c: full exclusive scan -> cursor (scatter turns it into row-end) ----------
__global__ void k_scanC(const int* __restrict__ counts, const int* __restrict__ boff,
                        int* __restrict__ cursor) {
    __shared__ int sm[256];
    int b = blockIdx.x, t = threadIdx.x;
    int i = b * 256 + t;
    int v = (i < NN) ? counts[i] : 0;
    sm[t] = v;
    __syncthreads();
    for (int s = 1; s < 256; s <<= 1) {
        int add = (t >= s) ? sm[t - s] : 0;
        __syncthreads();
        sm[t] += add;
        __syncthreads();
    }
    if (i < NN) cursor[i] = boff[b] + sm[t] - v;   // exclusive start
}

// ---------- K5: scatter src indices into CSR order (cursor becomes row-end) ----------
__global__ void k_scatter(const int* __restrict__ src, const int* __restrict__ dst,
                          int* cursor, int* __restrict__ csr_src) {
    int e = blockIdx.x * blockDim.x + threadIdx.x;
    if (e >= EE) return;
    int pos = atomicAdd(&cursor[dst[e]], 1);
    csr_src[pos] = src[e];
}

// ---------- K6: per-dst softmax+agg. wave=node, 4 groups of 16 lanes = 4 edges in flight,
//             lane owns 4 dims. No shuffles in inner loop; single pass (m=0 shift is exact).
__global__ __launch_bounds__(256) void k_aggcsr(
        const int* __restrict__ csr_src, const int* __restrict__ cursor_end,
        const int* __restrict__ counts,
        const float* __restrict__ s_src, const float* __restrict__ s_dst,
        const bf16* __restrict__ hg, float* __restrict__ agg) {
    int tid = threadIdx.x;
    int lane = tid & 63, wave = tid >> 6;
    int lane16 = lane & 15, grp = lane >> 4;
    int node = blockIdx.x * 4 + wave;
    if (node >= NN) return;
    int deg = counts[node];
    float a0 = 0.f, a1 = 0.f, a2 = 0.f, a3 = 0.f, denom = 0.f;
    if (deg) {
        int rs = cursor_end[node] - deg;
        float sd = s_dst[node];
        for (int i = grp; i < deg; i += 4) {
            int sv = csr_src[rs + i];
            float s = s_src[sv] + sd;
            s = (s >= 0.f) ? s : 0.2f * s;        // leaky_relu 0.2
            float ex = __expf(s);
            denom += ex;
            uint2 u = *(const uint2*)&hg[(size_t)sv * HH + lane16 * 4];
            float f0, f1, f2, f3;
            bf2x(u.x, f0, f1); bf2x(u.y, f2, f3);
            a0 = fmaf(ex, f0, a0); a1 = fmaf(ex, f1, a1);
            a2 = fmaf(ex, f2, a2); a3 = fmaf(ex, f3, a3);
        }
    }
    // combine the 4 groups (xor 16, 32); within-group lanes hold identical denom copies
    #pragma unroll
    for (int off = 16; off < 64; off <<= 1) {
        a0 += __shfl_xor(a0, off); a1 += __shfl_xor(a1, off);
        a2 += __shfl_xor(a2, off); a3 += __shfl_xor(a3, off);
        denom += __shfl_xor(denom, off);
    }
    if (lane < 16) {
        float inv = 1.f / (denom + 1e-9f);
        float4 r = make_float4(a0 * inv, a1 * inv, a2 * inv, a3 * inv);
        *(float4*)&agg[(size_t)node * HH + lane16 * 4] = r;
    }
}

// ---------- K7: xc = relu(agg); node head; bf16 p_src/p_dst partials ----------
// p_src aliases hg (bf16, same indexing; hg dead after K6). p_dst is separate.
__global__ __launch_bounds__(256) void k_nodehead(
        const float* __restrict__ agg,
        const float* __restrict__ Wn1, const float* __restrict__ bn1,
        const float* __restrict__ Wn2, const float* __restrict__ bn2,
        const float* __restrict__ We1,
        bf16* __restrict__ p_src, bf16* __restrict__ p_dst, float* __restrict__ out_node) {
    __shared__ float wn1[HH * HH];
    __shared__ float we1s[HH * HH];
    __shared__ float we1d[HH * HH];
    __shared__ float wn2[HH * NCLS];
    __shared__ float xcs[4][HH];
    int tid = threadIdx.x;
    for (int i = tid; i < HH * HH; i += 256) {
        wn1[i]  = Wn1[i];
        we1s[i] = We1[i];
        we1d[i] = We1[HH * HH + i];
    }
    if (tid < HH * NCLS) wn2[tid] = Wn2[tid];
    __syncthreads();
    int wave = tid >> 6, lane = tid & 63;
    for (int base = blockIdx.x * 4; base < NN; base += gridDim.x * 4) {
        int node = base + wave;
        bool valid = node < NN;
        if (valid) xcs[wave][lane] = fmaxf(agg[(size_t)node * HH + lane], 0.f);
        __syncthreads();
        if (valid) {
            float tn = bn1[lane], ps = 0.f, pd = 0.f;
            #pragma unroll 8
            for (int k = 0; k < HH; k++) {
                float xv = xcs[wave][k];
                tn = fmaf(xv, wn1[k * HH + lane], tn);
                ps = fmaf(xv, we1s[k * HH + lane], ps);
                pd = fmaf(xv, we1d[k * HH + lane], pd);
            }
            p_src[(size_t)node * HH + lane] = __float2bfloat16(ps);
            p_dst[(size_t)node * HH + lane] = __float2bfloat16(pd);
            tn = fmaxf(tn, 0.f);
            float l0 = tn * wn2[lane * NCLS + 0];
            float l1 = tn * wn2[lane * NCLS + 1];
            #pragma unroll
            for (int off = 32; off; off >>= 1) {
                l0 += __shfl_xor(l0, off);
                l1 += __shfl_xor(l1, off);
            }
            if (lane == 0) {
                out_node[node * NCLS + 0] = l0 + bn2[0];
                out_node[node * NCLS + 1] = l1 + bn2[1];
            }
        }
        __syncthreads();
    }
}

// ---------- K8: edge head. 16 lanes per edge, lane owns 4 dims; weights in registers.
__global__ __launch_bounds__(256) void k_edgehead(
        const int* __restrict__ src, const int* __restrict__ dst,
        const float* __restrict__ edge_attr,
        const bf16* __restrict__ p_src, const bf16* __restrict__ p_dst,
        const float* __restrict__ We1, const float* __restrict__ be1,
        const float* __restrict__ We2, const float* __restrict__ be2,
        float* __restrict__ out_edge) {
    int tid = threadIdx.x;
    int lane16 = tid & 15;
    int grp    = (tid & 63) >> 4;
    int wave   = tid >> 6;
    // register-resident weights for this lane's 4 dims
    float w1a[DEA][4], w2c0[4], w2c1[4], b1v[4];
    #pragma unroll
    for (int d = 0; d < DEA; d++) {
        float4 v = *(const float4*)&We1[(2 * HH + d) * HH + lane16 * 4];
        w1a[d][0] = v.x; w1a[d][1] = v.y; w1a[d][2] = v.z; w1a[d][3] = v.w;
    }
    float4 bv = *(const float4*)&be1[lane16 * 4];
    b1v[0] = bv.x; b1v[1] = bv.y; b1v[2] = bv.z; b1v[3] = bv.w;
    #pragma unroll
    for (int j = 0; j < 4; j++) {
        w2c0[j] = We2[(lane16 * 4 + j) * NCLS + 0];
        w2c1[j] = We2[(lane16 * 4 + j) * NCLS + 1];
    }
    float be20 = be2[0], be21 = be2[1];

    int stride = gridDim.x * 16;   // 16 edges per block-iteration
    for (int e = blockIdx.x * 16 + wave * 4 + grp; e < EE; e += stride) {
        int sv = src[e], dv = dst[e];
        uint2 us = *(const uint2*)&p_src[(size_t)sv * HH + lane16 * 4];
        uint2 ud = *(const uint2*)&p_dst[(size_t)dv * HH + lane16 * 4];
        float4 at0 = *(const float4*)&edge_attr[(size_t)e * DEA];
        float4 at1 = *(const float4*)&edge_attr[(size_t)e * DEA + 4];
        float av[DEA] = {at0.x, at0.y, at0.z, at0.w, at1.x, at1.y, at1.z, at1.w};
        float s0, s1, s2, s3, d0, d1, d2, d3;
        bf2x(us.x, s0, s1); bf2x(us.y, s2, s3);
        bf2x(ud.x, d0, d1); bf2x(ud.y, d2, d3);
        float t[4] = {s0 + d0 + b1v[0], s1 + d1 + b1v[1], s2 + d2 + b1v[2], s3 + d3 + b1v[3]};
        float l0 = 0.f, l1 = 0.f;
        #pragma unroll
        for (int j = 0; j < 4; j++) {
            #pragma unroll
            for (int d = 0; d < DEA; d++) t[j] = fmaf(av[d], w1a[d][j], t[j]);
            float r = fmaxf(t[j], 0.f);
            l0 = fmaf(r, w2c0[j], l0);
            l1 = fmaf(r, w2c1[j], l1);
        }
        #pragma unroll
        for (int off = 8; off; off >>= 1) {
            l0 += __shfl_xor(l0, off);
            l1 += __shfl_xor(l1, off);
        }
        if (lane16 == 0)
            *(float2*)&out_edge[(size_t)e * NCLS] = make_float2(l0 + be20, l1 + be21);
    }
}

extern "C" void kernel_launch(void* const* d_in, const int* in_sizes, int n_in,
                              void* d_out, int out_size, void* d_ws, size_t ws_size,
                              hipStream_t stream) {
    const float* x      = (const float*)d_in[0];
    const int*   ei     = (const int*)  d_in[1];
    const float* attr   = (const float*)d_in[2];
    const float* W_enc  = (const float*)d_in[3];
    const float* b_enc  = (const float*)d_in[4];
    const float* W_gat  = (const float*)d_in[5];
    const float* a_src  = (const float*)d_in[6];
    const float* a_dst  = (const float*)d_in[7];
    const float* Wn1    = (const float*)d_in[8];
    const float* bn1    = (const float*)d_in[9];
    const float* Wn2    = (const float*)d_in[10];
    const float* bn2    = (const float*)d_in[11];
    const float* We1    = (const float*)d_in[12];
    const float* be1    = (const float*)d_in[13];
    const float* We2    = (const float*)d_in[14];
    const float* be2    = (const float*)d_in[15];
    float* out = (float*)d_out;
    float* ws  = (float*)d_ws;

    // workspace layout (float units), total ~59 MB:
    bf16*  hg_psrc = (bf16*)ws;                        // [N*H] bf16: hg, later p_src
    float* agg     = ws + (size_t)NN * 32;             // [N*H] f32
    bf16*  p_dst   = (bf16*)(ws + (size_t)NN * 96);    // [N*H] bf16
    float* ssrc    = ws + (size_t)NN * 128;            // [N]
    float* sdst    = ssrc + NN;                        // [N]
    int*   counts  = (int*)(sdst + NN);                // [N]
    int*   cursor  = counts + NN;                      // [N] exclusive start -> row end
    int*   csr_src = cursor + NN;                      // [E]
    int*   bsum    = csr_src + EE;                     // [NBLK]
    int*   boff    = bsum + 512;                       // [NBLK]

    const int* srcp = ei;
    const int* dstp = ei + EE;

    hipMemsetAsync(counts, 0, NN * sizeof(int), stream);
    k_encode  <<<2048, 256, 0, stream>>>(x, W_enc, b_enc, W_gat, a_src, a_dst,
                                         hg_psrc, ssrc, sdst);
    k_hist    <<<(EE + 255) / 256, 256, 0, stream>>>(dstp, counts);
    k_scanA   <<<NBLK, 256, 0, stream>>>(counts, bsum);
    k_scanB   <<<1, 512, 0, stream>>>(bsum, boff);
    k_scanC   <<<NBLK, 256, 0, stream>>>(counts, boff, cursor);
    k_scatter <<<(EE + 255) / 256, 256, 0, stream>>>(srcp, dstp, cursor, csr_src);
    k_aggcsr  <<<(NN + 3) / 4, 256, 0, stream>>>(csr_src, cursor, counts,
                                                 ssrc, sdst, hg_psrc, agg);
    k_nodehead<<<2048, 256, 0, stream>>>(agg, Wn1, bn1, Wn2, bn2, We1,
                                         hg_psrc /*p_src*/, p_dst, out);
    k_edgehead<<<4096, 256, 0, stream>>>(srcp, dstp, attr, hg_psrc, p_dst,
                                         We1, be1, We2, be2, out + (size_t)NN * NCLS);
}

// Round 5
// 478.065 us; speedup vs baseline: 2.0679x; 1.2892x over previous
//
#include <hip/hip_runtime.h>
#include <hip/hip_bf16.h>

#define NN   100000
#define EE   1600000
#define DIN  128
#define HH   64
#define DEA  8
#define NCLS 2
#define NBLK ((NN + 255) / 256)   // 391 scan blocks
#define NPW  4                    // nodes per wave in encode/nodehead

typedef __hip_bfloat16 bf16;

// unpack uint = two packed bf16 (lo = low 16 bits, hi = high 16 bits)
__device__ __forceinline__ void bf2x(unsigned u, float& lo, float& hi) {
    union { unsigned i; float f; } a, b;
    a.i = u << 16; b.i = u & 0xffff0000u;
    lo = a.f; hi = b.f;
}

// ---------- K2: h = relu(x@W_enc+b); hg = h@W_gat (bf16); s_src/s_dst = hg . a ----------
// Wave processes NPW=4 nodes: weight LDS reads amortized x4, 4 independent FMA chains,
// x rows read via wave-uniform scalar loads. 16 nodes/block-iter; 100000%16==0 -> no tail.
__global__ __launch_bounds__(256) void k_encode(
        const float* __restrict__ x,
        const float* __restrict__ W_enc, const float* __restrict__ b_enc,
        const float* __restrict__ W_gat,
        const float* __restrict__ a_src, const float* __restrict__ a_dst,
        bf16* __restrict__ hg, float* __restrict__ s_src, float* __restrict__ s_dst) {
    __shared__ float wenc[DIN * HH];       // 32 KB
    __shared__ float wgat[HH * HH];        // 16 KB
    __shared__ float hbuf[16][HH];         // 4 KB, wave-private rows -> total 53248 B
    int tid = threadIdx.x;
    for (int i = tid; i < DIN * HH; i += 256) wenc[i] = W_enc[i];
    for (int i = tid; i < HH * HH; i += 256) wgat[i] = W_gat[i];
    int lane = tid & 63;
    int wv = __builtin_amdgcn_readfirstlane(tid >> 6);
    float biasl = b_enc[lane], avsl = a_src[lane], avdl = a_dst[lane];
    __syncthreads();
    for (int base = blockIdx.x * 16; base < NN; base += gridDim.x * 16) {
        int n0 = base + wv * NPW;
        const float* xr = x + (size_t)n0 * DIN;   // wave-uniform
        float h0 = biasl, h1 = biasl, h2 = biasl, h3 = biasl;
        #pragma unroll 4
        for (int d = 0; d < DIN; d++) {
            float w = wenc[d * HH + lane];
            h0 = fmaf(xr[d], w, h0);
            h1 = fmaf(xr[DIN + d], w, h1);
            h2 = fmaf(xr[2 * DIN + d], w, h2);
            h3 = fmaf(xr[3 * DIN + d], w, h3);
        }
        hbuf[wv * NPW + 0][lane] = fmaxf(h0, 0.f);
        hbuf[wv * NPW + 1][lane] = fmaxf(h1, 0.f);
        hbuf[wv * NPW + 2][lane] = fmaxf(h2, 0.f);
        hbuf[wv * NPW + 3][lane] = fmaxf(h3, 0.f);
        __syncthreads();
        float g[NPW] = {0.f, 0.f, 0.f, 0.f};
        #pragma unroll 4
        for (int k = 0; k < HH; k++) {
            float w = wgat[k * HH + lane];
            #pragma unroll
            for (int j = 0; j < NPW; j++) g[j] = fmaf(hbuf[wv * NPW + j][k], w, g[j]);
        }
        #pragma unroll
        for (int j = 0; j < NPW; j++) {
            hg[(size_t)(n0 + j) * HH + lane] = __float2bfloat16(g[j]);
            float ps = g[j] * avsl, pd = g[j] * avdl;
            #pragma unroll
            for (int off = 32; off; off >>= 1) {
                ps += __shfl_xor(ps, off);
                pd += __shfl_xor(pd, off);
            }
            if (lane == 0) { s_src[n0 + j] = ps; s_dst[n0 + j] = pd; }
        }
        __syncthreads();
    }
}

// ---------- K3: histogram of dst ----------
__global__ void k_hist(const int* __restrict__ dst, int* __restrict__ counts) {
    int e = blockIdx.x * blockDim.x + threadIdx.x;
    if (e < EE) atomicAdd(&counts[dst[e]], 1);
}

// ---------- K4a: per-block totals ----------
__global__ void k_scanA(const int* __restrict__ counts, int* __restrict__ bsum) {
    __shared__ int sm[256];
    int i = blockIdx.x * 256 + threadIdx.x;
    sm[threadIdx.x] = (i < NN) ? counts[i] : 0;
    __syncthreads();
    for (int s = 128; s; s >>= 1) {
        if (threadIdx.x < s) sm[threadIdx.x] += sm[threadIdx.x + s];
        __syncthreads();
    }
    if (threadIdx.x == 0) bsum[blockIdx.x] = sm[0];
}

// ---------- K4b: scan block totals (1 block, 512 threads; NBLK=391 < 512) ----------
__global__ void k_scanB(const int* __restrict__ bsum, int* __restrict__ boff) {
    __shared__ int sm[512];
    int t = threadIdx.x;
    int v = (t < NBLK) ? bsum[t] : 0;
    sm[t] = v;
    __syncthreads();
    for (int s = 1; s < 512; s <<= 1) {
        int add = (t >= s) ? sm[t - s] : 0;
        __syncthreads();
        sm[t] += add;
        __syncthreads();
    }
    if (t < NBLK) boff[t] = sm[t] - v;   // exclusive prefix of block totals
}

// ---------- K4c: full exclusive scan -> cursor (scatter turns it into row-end) ----------
__global__ void k_scanC(const int* __restrict__ counts, const int* __restrict__ boff,
                        int* __restrict__ cursor) {
    __shared__ int sm[256];
    int b = blockIdx.x, t = threadIdx.x;
    int i = b * 256 + t;
    int v = (i < NN) ? counts[i] : 0;
    sm[t] = v;
    __syncthreads();
    for (int s = 1; s < 256; s <<= 1) {
        int add = (t >= s) ? sm[t - s] : 0;
        __syncthreads();
        sm[t] += add;
        __syncthreads();
    }
    if (i < NN) cursor[i] = boff[b] + sm[t] - v;   // exclusive start
}

// ---------- K5: scatter src indices into CSR order (cursor becomes row-end) ----------
__global__ void k_scatter(const int* __restrict__ src, const int* __restrict__ dst,
                          int* cursor, int* __restrict__ csr_src) {
    int e = blockIdx.x * blockDim.x + threadIdx.x;
    if (e >= EE) return;
    int pos = atomicAdd(&cursor[dst[e]], 1);
    csr_src[pos] = src[e];
}

// ---------- K6: per-dst softmax+agg. wave=node, 8 groups of 8 lanes = 8 edges in flight,
//             lane owns 8 dims (uint4 16B gather). Single pass (m=0 shift is exact:
//             scores bounded, softmax shift-invariant).
__global__ __launch_bounds__(256) void k_aggcsr(
        const int* __restrict__ csr_src, const int* __restrict__ cursor_end,
        const int* __restrict__ counts,
        const float* __restrict__ s_src, const float* __restrict__ s_dst,
        const bf16* __restrict__ hg, float* __restrict__ agg) {
    int tid = threadIdx.x;
    int lane = tid & 63, wave = tid >> 6;
    int lane8 = lane & 7, grp = lane >> 3;
    int node = blockIdx.x * 4 + wave;
    if (node >= NN) return;
    int deg = counts[node];
    float a[8] = {0.f}, denom = 0.f;
    if (deg) {
        int rs = cursor_end[node] - deg;
        float sd = s_dst[node];
        for (int i = grp; i < deg; i += 8) {
            int sv = csr_src[rs + i];
            float s = s_src[sv] + sd;
            s = (s >= 0.f) ? s : 0.2f * s;        // leaky_relu 0.2
            float ex = __expf(s);
            denom += ex;
            uint4 u = *(const uint4*)&hg[(size_t)sv * HH + lane8 * 8];
            float f0, f1, f2, f3, f4, f5, f6, f7;
            bf2x(u.x, f0, f1); bf2x(u.y, f2, f3);
            bf2x(u.z, f4, f5); bf2x(u.w, f6, f7);
            a[0] = fmaf(ex, f0, a[0]); a[1] = fmaf(ex, f1, a[1]);
            a[2] = fmaf(ex, f2, a[2]); a[3] = fmaf(ex, f3, a[3]);
            a[4] = fmaf(ex, f4, a[4]); a[5] = fmaf(ex, f5, a[5]);
            a[6] = fmaf(ex, f6, a[6]); a[7] = fmaf(ex, f7, a[7]);
        }
    }
    // combine the 8 groups (xor 8,16,32); within-group lanes hold identical denom copies
    #pragma unroll
    for (int off = 8; off < 64; off <<= 1) {
        #pragma unroll
        for (int j = 0; j < 8; j++) a[j] += __shfl_xor(a[j], off);
        denom += __shfl_xor(denom, off);
    }
    if (lane < 8) {
        float inv = 1.f / (denom + 1e-9f);
        float4 r0 = make_float4(a[0] * inv, a[1] * inv, a[2] * inv, a[3] * inv);
        float4 r1 = make_float4(a[4] * inv, a[5] * inv, a[6] * inv, a[7] * inv);
        *(float4*)&agg[(size_t)node * HH + lane8 * 8]     = r0;
        *(float4*)&agg[(size_t)node * HH + lane8 * 8 + 4] = r1;
    }
}

// ---------- K7: xc = relu(agg); node head; bf16 p_src/p_dst partials ----------
// Same 4-nodes-per-wave structure as k_encode. p_src aliases hg (dead after K6).
__global__ __launch_bounds__(256) void k_nodehead(
        const float* __restrict__ agg,
        const float* __restrict__ Wn1, const float* __restrict__ bn1,
        const float* __restrict__ Wn2, const float* __restrict__ bn2,
        const float* __restrict__ We1,
        bf16* __restrict__ p_src, bf16* __restrict__ p_dst, float* __restrict__ out_node) {
    __shared__ float wn1[HH * HH];     // 16 KB
    __shared__ float we1s[HH * HH];    // 16 KB
    __shared__ float we1d[HH * HH];    // 16 KB
    __shared__ float xbuf[16][HH];     // 4 KB -> total 53248 B
    int tid = threadIdx.x;
    for (int i = tid; i < HH * HH; i += 256) {
        wn1[i]  = Wn1[i];
        we1s[i] = We1[i];
        we1d[i] = We1[HH * HH + i];
    }
    int lane = tid & 63;
    int wv = __builtin_amdgcn_readfirstlane(tid >> 6);
    float bn1l = bn1[lane];
    float wn2a = Wn2[lane * NCLS + 0], wn2b = Wn2[lane * NCLS + 1];
    float bn20 = bn2[0], bn21 = bn2[1];
    __syncthreads();
    for (int base = blockIdx.x * 16; base < NN; base += gridDim.x * 16) {
        int n0 = base + wv * NPW;
        #pragma unroll
        for (int j = 0; j < NPW; j++)
            xbuf[wv * NPW + j][lane] = fmaxf(agg[(size_t)(n0 + j) * HH + lane], 0.f);
        __syncthreads();
        float tn[NPW], ps[NPW], pd[NPW];
        #pragma unroll
        for (int j = 0; j < NPW; j++) { tn[j] = bn1l; ps[j] = 0.f; pd[j] = 0.f; }
        #pragma unroll 4
        for (int k = 0; k < HH; k++) {
            float w1 = wn1[k * HH + lane];
            float ws = we1s[k * HH + lane];
            float wd = we1d[k * HH + lane];
            #pragma unroll
            for (int j = 0; j < NPW; j++) {
                float xv = xbuf[wv * NPW + j][k];
                tn[j] = fmaf(xv, w1, tn[j]);
                ps[j] = fmaf(xv, ws, ps[j]);
                pd[j] = fmaf(xv, wd, pd[j]);
            }
        }
        #pragma unroll
        for (int j = 0; j < NPW; j++) {
            int node = n0 + j;
            p_src[(size_t)node * HH + lane] = __float2bfloat16(ps[j]);
            p_dst[(size_t)node * HH + lane] = __float2bfloat16(pd[j]);
            float r = fmaxf(tn[j], 0.f);
            float l0 = r * wn2a, l1 = r * wn2b;
            #pragma unroll
            for (int off = 32; off; off >>= 1) {
                l0 += __shfl_xor(l0, off);
                l1 += __shfl_xor(l1, off);
            }
            if (lane == 0)
                *(float2*)&out_node[(size_t)node * NCLS] = make_float2(l0 + bn20, l1 + bn21);
        }
        __syncthreads();
    }
}

// ---------- K8: edge head. 16 lanes per edge-pair (2 edges/group/iter), weights in regs.
// 32 edges per block-iter; EE%32==0 -> both edges of a pair always valid.
__global__ __launch_bounds__(256) void k_edgehead(
        const int* __restrict__ src, const int* __restrict__ dst,
        const float* __restrict__ edge_attr,
        const bf16* __restrict__ p_src, const bf16* __restrict__ p_dst,
        const float* __restrict__ We1, const float* __restrict__ be1,
        const float* __restrict__ We2, const float* __restrict__ be2,
        float* __restrict__ out_edge) {
    int tid = threadIdx.x;
    int lane16 = tid & 15;
    int grp    = (tid & 63) >> 4;
    int wave   = tid >> 6;
    // register-resident weights for this lane's 4 dims
    float w1a[DEA][4], w2c0[4], w2c1[4], b1v[4];
    #pragma unroll
    for (int d = 0; d < DEA; d++) {
        float4 v = *(const float4*)&We1[(2 * HH + d) * HH + lane16 * 4];
        w1a[d][0] = v.x; w1a[d][1] = v.y; w1a[d][2] = v.z; w1a[d][3] = v.w;
    }
    float4 bv = *(const float4*)&be1[lane16 * 4];
    b1v[0] = bv.x; b1v[1] = bv.y; b1v[2] = bv.z; b1v[3] = bv.w;
    #pragma unroll
    for (int j = 0; j < 4; j++) {
        w2c0[j] = We2[(lane16 * 4 + j) * NCLS + 0];
        w2c1[j] = We2[(lane16 * 4 + j) * NCLS + 1];
    }
    float be20 = be2[0], be21 = be2[1];

    int stride = gridDim.x * 32;   // 32 edges per block-iteration
    for (int e = blockIdx.x * 32 + wave * 8 + grp * 2; e < EE; e += stride) {
        int ea = e, eb = e + 1;
        int sva = src[ea], dva = dst[ea];
        int svb = src[eb], dvb = dst[eb];
        uint2 usa = *(const uint2*)&p_src[(size_t)sva * HH + lane16 * 4];
        uint2 uda = *(const uint2*)&p_dst[(size_t)dva * HH + lane16 * 4];
        uint2 usb = *(const uint2*)&p_src[(size_t)svb * HH + lane16 * 4];
        uint2 udb = *(const uint2*)&p_dst[(size_t)dvb * HH + lane16 * 4];
        float4 aa0 = *(const float4*)&edge_attr[(size_t)ea * DEA];
        float4 aa1 = *(const float4*)&edge_attr[(size_t)ea * DEA + 4];
        float4 ab0 = *(const float4*)&edge_attr[(size_t)eb * DEA];
        float4 ab1 = *(const float4*)&edge_attr[(size_t)eb * DEA + 4];
        float ava[DEA] = {aa0.x, aa0.y, aa0.z, aa0.w, aa1.x, aa1.y, aa1.z, aa1.w};
        float avb[DEA] = {ab0.x, ab0.y, ab0.z, ab0.w, ab1.x, ab1.y, ab1.z, ab1.w};
        float sa0, sa1, sa2, sa3, da0, da1, da2, da3;
        float sb0, sb1, sb2, sb3, db0, db1, db2, db3;
        bf2x(usa.x, sa0, sa1); bf2x(usa.y, sa2, sa3);
        bf2x(uda.x, da0, da1); bf2x(uda.y, da2, da3);
        bf2x(usb.x, sb0, sb1); bf2x(usb.y, sb2, sb3);
        bf2x(udb.x, db0, db1); bf2x(udb.y, db2, db3);
        float ta[4] = {sa0 + da0 + b1v[0], sa1 + da1 + b1v[1],
                       sa2 + da2 + b1v[2], sa3 + da3 + b1v[3]};
        float tb[4] = {sb0 + db0 + b1v[0], sb1 + db1 + b1v[1],
                       sb2 + db2 + b1v[2], sb3 + db3 + b1v[3]};
        float l0a = 0.f, l1a = 0.f, l0b = 0.f, l1b = 0.f;
        #pragma unroll
        for (int j = 0; j < 4; j++) {
            #pragma unroll
            for (int d = 0; d < DEA; d++) {
                ta[j] = fmaf(ava[d], w1a[d][j], ta[j]);
                tb[j] = fmaf(avb[d], w1a[d][j], tb[j]);
            }
            float ra = fmaxf(ta[j], 0.f), rb = fmaxf(tb[j], 0.f);
            l0a = fmaf(ra, w2c0[j], l0a); l1a = fmaf(ra, w2c1[j], l1a);
            l0b = fmaf(rb, w2c0[j], l0b); l1b = fmaf(rb, w2c1[j], l1b);
        }
        #pragma unroll
        for (int off = 8; off; off >>= 1) {
            l0a += __shfl_xor(l0a, off); l1a += __shfl_xor(l1a, off);
            l0b += __shfl_xor(l0b, off); l1b += __shfl_xor(l1b, off);
        }
        if (lane16 == 0) {
            *(float2*)&out_edge[(size_t)ea * NCLS] = make_float2(l0a + be20, l1a + be21);
            *(float2*)&out_edge[(size_t)eb * NCLS] = make_float2(l0b + be20, l1b + be21);
        }
    }
}

extern "C" void kernel_launch(void* const* d_in, const int* in_sizes, int n_in,
                              void* d_out, int out_size, void* d_ws, size_t ws_size,
                              hipStream_t stream) {
    const float* x      = (const float*)d_in[0];
    const int*   ei     = (const int*)  d_in[1];
    const float* attr   = (const float*)d_in[2];
    const float* W_enc  = (const float*)d_in[3];
    const float* b_enc  = (const float*)d_in[4];
    const float* W_gat  = (const float*)d_in[5];
    const float* a_src  = (const float*)d_in[6];
    const float* a_dst  = (const float*)d_in[7];
    const float* Wn1    = (const float*)d_in[8];
    const float* bn1    = (const float*)d_in[9];
    const float* Wn2    = (const float*)d_in[10];
    const float* bn2    = (const float*)d_in[11];
    const float* We1    = (const float*)d_in[12];
    const float* be1    = (const float*)d_in[13];
    const float* We2    = (const float*)d_in[14];
    const float* be2    = (const float*)d_in[15];
    float* out = (float*)d_out;
    float* ws  = (float*)d_ws;

    // workspace layout (float units), total ~59 MB:
    bf16*  hg_psrc = (bf16*)ws;                        // [N*H] bf16: hg, later p_src
    float* agg     = ws + (size_t)NN * 32;             // [N*H] f32
    bf16*  p_dst   = (bf16*)(ws + (size_t)NN * 96);    // [N*H] bf16
    float* ssrc    = ws + (size_t)NN * 128;            // [N]
    float* sdst    = ssrc + NN;                        // [N]
    int*   counts  = (int*)(sdst + NN);                // [N]
    int*   cursor  = counts + NN;                      // [N] exclusive start -> row end
    int*   csr_src = cursor + NN;                      // [E]
    int*   bsum    = csr_src + EE;                     // [NBLK]
    int*   boff    = bsum + 512;                       // [NBLK]

    const int* srcp = ei;
    const int* dstp = ei + EE;

    hipMemsetAsync(counts, 0, NN * sizeof(int), stream);
    k_encode  <<<2048, 256, 0, stream>>>(x, W_enc, b_enc, W_gat, a_src, a_dst,
                                         hg_psrc, ssrc, sdst);
    k_hist    <<<(EE + 255) / 256, 256, 0, stream>>>(dstp, counts);
    k_scanA   <<<NBLK, 256, 0, stream>>>(counts, bsum);
    k_scanB   <<<1, 512, 0, stream>>>(bsum, boff);
    k_scanC   <<<NBLK, 256, 0, stream>>>(counts, boff, cursor);
    k_scatter <<<(EE + 255) / 256, 256, 0, stream>>>(srcp, dstp, cursor, csr_src);
    k_aggcsr  <<<(NN + 3) / 4, 256, 0, stream>>>(csr_src, cursor, counts,
                                                 ssrc, sdst, hg_psrc, agg);
    k_nodehead<<<2048, 256, 0, stream>>>(agg, Wn1, bn1, Wn2, bn2, We1,
                                         hg_psrc /*p_src*/, p_dst, out);
    k_edgehead<<<8192, 256, 0, stream>>>(srcp, dstp, attr, hg_psrc, p_dst,
                                         We1, be1, We2, be2, out + (size_t)NN * NCLS);
}